// Round 3
// baseline (164.152 us; speedup 1.0000x reference)
//
#include <hip/hip_runtime.h>
#include <stdint.h>

#define D_IN 2048
#define D_H  512
#define WORDS 32            // D_IN / 64
#define NCH 8               // k-chunks of 256
#define RPW 4               // rows per wave
#define BM  16              // rows per block (4 waves)

// Pack sign bits of W, transposed, in the permuted bit order the x-pack
// produces: word w = ch*4 + j (ch=0..7), bit p  <->  W[ch*256 + 4p + j][c].
__global__ __launch_bounds__(512) void pack_w_kernel(
    const float* __restrict__ W, unsigned long long* __restrict__ wb) {
  const int w = blockIdx.x;   // 0..31
  const int c = threadIdx.x;  // 0..511
  const int ch = w >> 2;
  const int j  = w & 3;
  unsigned long long bits = 0ull;
#pragma unroll 16
  for (int p = 0; p < 64; ++p) {
    float v = W[(size_t)(ch * 256 + 4 * p + j) * D_H + c];
    bits |= (unsigned long long)(v < 0.0f) << p;
  }
  wb[(size_t)w * D_H + c] = bits;
}

// Barrier-free, LDS-free binary GEMM.
// Wave owns 4 rows x 512 cols. X sign-bits live in SGPRs via __ballot
// (wave-uniform). Lane l owns cols [4l,4l+4) and [256+4l, 256+4l+4).
// Pipeline per chunk: issue next X loads -> popcount compute -> ballot-commit
// (vmcnt wait lands after compute; T14 split, no barriers anywhere).
__global__ __launch_bounds__(256, 4) void bgemm_kernel(
    const float* __restrict__ X,
    const unsigned long long* __restrict__ wb,
    const float* __restrict__ b, const float* __restrict__ beta,
    const float* __restrict__ mm, const float* __restrict__ mv,
    float* __restrict__ out) {
  const int tid = threadIdx.x;
  const int wv  = tid >> 6;
  const int l   = tid & 63;
  const size_t m0 = (size_t)blockIdx.x * BM + (size_t)wv * RPW;

  const float4* X4 = (const float4*)X;

  unsigned long long sx[RPW][4];  // wave-uniform -> SGPRs
  float4 v[RPW];                  // staged next-chunk X (VGPRs)

  // prologue: chunk 0
#pragma unroll
  for (int i = 0; i < RPW; ++i) v[i] = X4[(m0 + i) * (D_IN / 4) + l];
#pragma unroll
  for (int i = 0; i < RPW; ++i) {
    sx[i][0] = __ballot(v[i].x < 0.0f);
    sx[i][1] = __ballot(v[i].y < 0.0f);
    sx[i][2] = __ballot(v[i].z < 0.0f);
    sx[i][3] = __ballot(v[i].w < 0.0f);
  }

  unsigned acc[RPW][8];
#pragma unroll
  for (int i = 0; i < RPW; ++i)
#pragma unroll
    for (int j = 0; j < 8; ++j) acc[i][j] = 0u;

  // compute one chunk from sx; wl streamed from L1/L2
  auto compute_chunk = [&](int ch) {
#pragma unroll
    for (int w = 0; w < 4; ++w) {
      const unsigned long long* wrow = wb + (size_t)(ch * 4 + w) * D_H;
      ulonglong2 a0 = *(const ulonglong2*)(wrow + 4 * (size_t)l);
      ulonglong2 a1 = *(const ulonglong2*)(wrow + 4 * (size_t)l + 2);
#pragma unroll
      for (int i = 0; i < RPW; ++i) {
        acc[i][0] += (unsigned)__popcll(sx[i][w] ^ a0.x);
        acc[i][1] += (unsigned)__popcll(sx[i][w] ^ a0.y);
        acc[i][2] += (unsigned)__popcll(sx[i][w] ^ a1.x);
        acc[i][3] += (unsigned)__popcll(sx[i][w] ^ a1.y);
      }
      ulonglong2 b0 = *(const ulonglong2*)(wrow + 256 + 4 * (size_t)l);
      ulonglong2 b1 = *(const ulonglong2*)(wrow + 256 + 4 * (size_t)l + 2);
#pragma unroll
      for (int i = 0; i < RPW; ++i) {
        acc[i][4] += (unsigned)__popcll(sx[i][w] ^ b0.x);
        acc[i][5] += (unsigned)__popcll(sx[i][w] ^ b0.y);
        acc[i][6] += (unsigned)__popcll(sx[i][w] ^ b1.x);
        acc[i][7] += (unsigned)__popcll(sx[i][w] ^ b1.y);
      }
    }
  };

#pragma unroll 1
  for (int ch = 0; ch < NCH - 1; ++ch) {
    // issue next chunk's X loads (VMEM only; consumed after compute)
#pragma unroll
    for (int i = 0; i < RPW; ++i)
      v[i] = X4[(m0 + i) * (D_IN / 4) + (size_t)(ch + 1) * 64 + l];

    compute_chunk(ch);

    // commit ballots for next chunk (vmcnt wait lands here)
#pragma unroll
    for (int i = 0; i < RPW; ++i) {
      sx[i][0] = __ballot(v[i].x < 0.0f);
      sx[i][1] = __ballot(v[i].y < 0.0f);
      sx[i][2] = __ballot(v[i].z < 0.0f);
      sx[i][3] = __ballot(v[i].w < 0.0f);
    }
  }
  compute_chunk(NCH - 1);

  // epilogue: y = (K - 2*diff) + b; out = (y - mean)/sqrt(var+eps) + beta
  {  // cols 4l .. 4l+3
    float4 bA = ((const float4*)b)[l];
    float4 mA = ((const float4*)mm)[l];
    float4 eA = ((const float4*)beta)[l];
    float4 vA = ((const float4*)mv)[l];
    float i0 = 1.0f / sqrtf(vA.x + 1e-3f);
    float i1 = 1.0f / sqrtf(vA.y + 1e-3f);
    float i2 = 1.0f / sqrtf(vA.z + 1e-3f);
    float i3 = 1.0f / sqrtf(vA.w + 1e-3f);
#pragma unroll
    for (int i = 0; i < RPW; ++i) {
      float4 o;
      o.x = ((float)(D_IN - 2 * (int)acc[i][0]) + bA.x - mA.x) * i0 + eA.x;
      o.y = ((float)(D_IN - 2 * (int)acc[i][1]) + bA.y - mA.y) * i1 + eA.y;
      o.z = ((float)(D_IN - 2 * (int)acc[i][2]) + bA.z - mA.z) * i2 + eA.z;
      o.w = ((float)(D_IN - 2 * (int)acc[i][3]) + bA.w - mA.w) * i3 + eA.w;
      *(float4*)(out + (m0 + i) * D_H + 4 * (size_t)l) = o;  // contiguous 1KB
    }
  }
  {  // cols 256+4l .. 256+4l+3
    float4 bB = ((const float4*)b)[64 + l];
    float4 mB = ((const float4*)mm)[64 + l];
    float4 eB = ((const float4*)beta)[64 + l];
    float4 vB = ((const float4*)mv)[64 + l];
    float i0 = 1.0f / sqrtf(vB.x + 1e-3f);
    float i1 = 1.0f / sqrtf(vB.y + 1e-3f);
    float i2 = 1.0f / sqrtf(vB.z + 1e-3f);
    float i3 = 1.0f / sqrtf(vB.w + 1e-3f);
#pragma unroll
    for (int i = 0; i < RPW; ++i) {
      float4 o;
      o.x = ((float)(D_IN - 2 * (int)acc[i][4]) + bB.x - mB.x) * i0 + eB.x;
      o.y = ((float)(D_IN - 2 * (int)acc[i][5]) + bB.y - mB.y) * i1 + eB.y;
      o.z = ((float)(D_IN - 2 * (int)acc[i][6]) + bB.z - mB.z) * i2 + eB.z;
      o.w = ((float)(D_IN - 2 * (int)acc[i][7]) + bB.w - mB.w) * i3 + eB.w;
      *(float4*)(out + (m0 + i) * D_H + 256 + 4 * (size_t)l) = o;
    }
  }
}

extern "C" void kernel_launch(void* const* d_in, const int* in_sizes, int n_in,
                              void* d_out, int out_size, void* d_ws, size_t ws_size,
                              hipStream_t stream) {
  const float* X    = (const float*)d_in[0];  // [32768, 2048]
  const float* W    = (const float*)d_in[1];  // [2048, 512]
  const float* b    = (const float*)d_in[2];  // [512]
  const float* beta = (const float*)d_in[3];  // [512]
  const float* mm   = (const float*)d_in[4];  // [512]
  const float* mv   = (const float*)d_in[5];  // [512]
  float* out = (float*)d_out;                 // [32768, 512]

  unsigned long long* wbits = (unsigned long long*)d_ws;  // 128 KB

  pack_w_kernel<<<dim3(WORDS), dim3(D_H), 0, stream>>>(W, wbits);

  const int M = in_sizes[0] / D_IN;  // 32768
  bgemm_kernel<<<dim3(M / BM), dim3(256), 0, stream>>>(X, wbits, b, beta, mm, mv, out);
}